// Round 2
// baseline (275.668 us; speedup 1.0000x reference)
//
#include <hip/hip_runtime.h>

#define N_ROWS   65536
#define DIM      64
#define K_CODES  1024
#define TOTAL_ELEMS 4194304   // N_ROWS * DIM

// ---------------- ws layout (4-byte elements) ----------------
// [0      , 1024 )  code norms ||e_k||^2 (float, numpy-order)
// [1024   , 66560)  indices     (int)
// [66560  , 67584)  counts      (int)
// [67584  , 71680)  loss partials (float, 4096)
// [71680  , 137216) codebook transposed cbT[k][d] (float)

// Precompute ||e_k||^2 in numpy's axis-0 reduce order (strictly sequential,
// no FMA contraction), transpose codebook, zero histogram counts.
__global__ __launch_bounds__(256) void k_prep(const float* __restrict__ cb,
                                              float* __restrict__ norms,
                                              int* __restrict__ counts,
                                              float* __restrict__ cbT) {
    int k = blockIdx.x * 256 + threadIdx.x;   // 4 blocks -> 1024
    float v0 = cb[k];
    float s = __fmul_rn(v0, v0);
    cbT[k * DIM] = v0;
#pragma unroll
    for (int d = 1; d < DIM; ++d) {
        float v = cb[d * K_CODES + k];
        s = __fadd_rn(s, __fmul_rn(v, v));
        cbT[k * DIM + d] = v;
    }
    norms[k] = s;
    counts[k] = 0;
}

// Argmin over codes, emulating the reference fp32 computation:
//   dist = fl32( fl32(xx_np + ee_np) - fl32(2 * fl32(dot)) )
// xx_np = numpy pairwise sum of squares (n=64 path), dot computed in fp64.
// Block: 512 threads, 128 rows x 1024 codes (16 chunks of 64 codes).
// Per thread: 8 rows x 2 codes per chunk.
__global__ __launch_bounds__(512) void k_assign(const float* __restrict__ x,
                                                const float* __restrict__ cb,
                                                const float* __restrict__ norms,
                                                int* __restrict__ idx_out,
                                                float* __restrict__ idxf_out) {
    __shared__ float xs[128][68];    // 34816 B
    __shared__ float cbsT[64][68];   // 17408 B, chunk of codebook [k][d]
    __shared__ float xxs[128];

    const int tid = threadIdx.x;
    const int tr = tid >> 5;    // 0..15 row group
    const int tc = tid & 31;    // 0..31 code group
    const int r0 = blockIdx.x * 128;

    // Load X tile: 128 rows x 64 d (2048 float4, 4 iters)
#pragma unroll
    for (int i = 0; i < 4; ++i) {
        int e  = i * 512 + tid;
        int r  = e >> 4;              // 16 float4 per row
        int dc = (e & 15) << 2;
        float4 v = *reinterpret_cast<const float4*>(x + (size_t)(r0 + r) * DIM + dc);
        *reinterpret_cast<float4*>(&xs[r][dc]) = v;
    }
    __syncthreads();

    // xx per row: replicate numpy pairwise_sum (n=64, 8 accumulators stride 8,
    // then ((r0+r1)+(r2+r3))+((r4+r5)+(r6+r7))), no FMA contraction.
    if (tid < 128) {
        float r[8];
#pragma unroll
        for (int j = 0; j < 8; ++j) {
            float v = xs[tid][j];
            r[j] = __fmul_rn(v, v);
        }
#pragma unroll
        for (int m = 1; m < 8; ++m)
#pragma unroll
            for (int j = 0; j < 8; ++j) {
                float v = xs[tid][8 * m + j];
                r[j] = __fadd_rn(r[j], __fmul_rn(v, v));
            }
        float t01 = __fadd_rn(r[0], r[1]);
        float t23 = __fadd_rn(r[2], r[3]);
        float t45 = __fadd_rn(r[4], r[5]);
        float t67 = __fadd_rn(r[6], r[7]);
        xxs[tid] = __fadd_rn(__fadd_rn(t01, t23), __fadd_rn(t45, t67));
    }

    float minv[8];
    int   mink[8];
#pragma unroll
    for (int i = 0; i < 8; ++i) { minv[i] = 3.4e38f; mink[i] = 0; }

    for (int c = 0; c < 16; ++c) {
        __syncthreads();   // protect cbsT restage; also covers xs/xxs for c=0
        // stage 64 codes x 64 dims transposed: cbsT[j][d] = cb[d][c*64+j]
#pragma unroll
        for (int i = 0; i < 8; ++i) {
            int e = i * 512 + tid;    // 0..4095
            int d = e >> 6;
            int j = e & 63;
            cbsT[j][d] = cb[d * K_CODES + c * 64 + j];
        }
        __syncthreads();

        double acc[8][2];
#pragma unroll
        for (int i = 0; i < 8; ++i) { acc[i][0] = 0.0; acc[i][1] = 0.0; }

        for (int d = 0; d < DIM; d += 4) {
            float4 cf0 = *reinterpret_cast<const float4*>(&cbsT[tc][d]);
            float4 cf1 = *reinterpret_cast<const float4*>(&cbsT[tc + 32][d]);
#pragma unroll
            for (int i = 0; i < 8; ++i) {
                float4 xf = *reinterpret_cast<const float4*>(&xs[tr + 16 * i][d]);
                acc[i][0] += (double)xf.x * (double)cf0.x;
                acc[i][0] += (double)xf.y * (double)cf0.y;
                acc[i][0] += (double)xf.z * (double)cf0.z;
                acc[i][0] += (double)xf.w * (double)cf0.w;
                acc[i][1] += (double)xf.x * (double)cf1.x;
                acc[i][1] += (double)xf.y * (double)cf1.y;
                acc[i][1] += (double)xf.z * (double)cf1.z;
                acc[i][1] += (double)xf.w * (double)cf1.w;
            }
        }

        // distance emulation in reference order
#pragma unroll
        for (int n = 0; n < 2; ++n) {
            int k = c * 64 + tc + 32 * n;   // ascending k within thread scan
            float ee = norms[k];
#pragma unroll
            for (int i = 0; i < 8; ++i) {
                float mf = (float)acc[i][n];                       // fl32(exact dot)
                float dist = __fsub_rn(__fadd_rn(xxs[tr + 16 * i], ee),
                                       __fmul_rn(2.0f, mf));
                if (dist < minv[i]) { minv[i] = dist; mink[i] = k; }  // strict <
            }
        }
    }

    // reduce argmin across the 32 tc lanes of each row group (tie -> lowest k)
#pragma unroll
    for (int i = 0; i < 8; ++i) {
        float v = minv[i];
        int   k = mink[i];
#pragma unroll
        for (int off = 16; off >= 1; off >>= 1) {
            float v2 = __shfl_xor(v, off);
            int   k2 = __shfl_xor(k, off);
            if (v2 < v || (v2 == v && k2 < k)) { v = v2; k = k2; }
        }
        if (tc == 0) {
            int row = r0 + tr + 16 * i;
            idx_out[row]  = k;
            idxf_out[row] = (float)k;
        }
    }
}

// Gather quantized vectors, write STE output, per-block partial of sum((q-x)^2)
__global__ __launch_bounds__(256) void k_quant(const float* __restrict__ x,
                                               const float* __restrict__ cbT,
                                               const int* __restrict__ idx,
                                               float* __restrict__ ste,
                                               float* __restrict__ partials) {
    int t  = blockIdx.x * 256 + threadIdx.x;
    int e  = t << 2;
    int n  = e >> 6;
    int dc = e & 63;
    float4 xv = *reinterpret_cast<const float4*>(x + e);
    int k = idx[n];
    float4 qv = *reinterpret_cast<const float4*>(cbT + (size_t)k * DIM + dc);

    float4 sv;  // ste = x + (q - x): match reference rounding order
    sv.x = xv.x + (qv.x - xv.x);
    sv.y = xv.y + (qv.y - xv.y);
    sv.z = xv.z + (qv.z - xv.z);
    sv.w = xv.w + (qv.w - xv.w);
    *reinterpret_cast<float4*>(ste + e) = sv;

    float dx = qv.x - xv.x, dy = qv.y - xv.y, dz = qv.z - xv.z, dw = qv.w - xv.w;
    float s = dx * dx + dy * dy + dz * dz + dw * dw;

#pragma unroll
    for (int off = 32; off >= 1; off >>= 1) s += __shfl_down(s, off);
    __shared__ float red[4];
    int wave = threadIdx.x >> 6, lane = threadIdx.x & 63;
    if (lane == 0) red[wave] = s;
    __syncthreads();
    if (threadIdx.x == 0)
        partials[blockIdx.x] = (red[0] + red[1]) + (red[2] + red[3]);
}

__global__ __launch_bounds__(256) void k_hist(const int* __restrict__ idx,
                                              int* __restrict__ counts) {
    int t = blockIdx.x * 256 + threadIdx.x;   // 256 blocks -> 65536
    atomicAdd(&counts[idx[t]], 1);            // integer: deterministic
}

// Single block: final loss sum (fixed order), entropy, perplexity.
__global__ __launch_bounds__(1024) void k_final(const float* __restrict__ partials,
                                                const int* __restrict__ counts,
                                                float* __restrict__ out_scalars) {
    int tid = threadIdx.x;      // 1024 threads
    float s = 0.f;
    for (int i = tid; i < 4096; i += 1024) s += partials[i];
#pragma unroll
    for (int off = 32; off >= 1; off >>= 1) s += __shfl_down(s, off);
    __shared__ float wsum[16];
    int wave = tid >> 6, lane = tid & 63;
    if (lane == 0) wsum[wave] = s;

    float c = (float)counts[tid];
    float p = c * (1.0f / 65536.0f);
    float t = -p * logf(p + 1e-10f);
#pragma unroll
    for (int off = 32; off >= 1; off >>= 1) t += __shfl_down(t, off);
    __shared__ float esum[16];
    if (lane == 0) esum[wave] = t;
    __syncthreads();

    if (tid == 0) {
        float total = 0.f, ent = 0.f;
        for (int w = 0; w < 16; ++w) { total += wsum[w]; ent += esum[w]; }
        float mean = total * (1.0f / (float)TOTAL_ELEMS);
        out_scalars[0] = expf(ent);      // perplexity
        out_scalars[1] = mean;           // codebook_loss
        out_scalars[2] = 0.25f * mean;   // commitment_loss
    }
}

extern "C" void kernel_launch(void* const* d_in, const int* in_sizes, int n_in,
                              void* d_out, int out_size, void* d_ws, size_t ws_size,
                              hipStream_t stream) {
    const float* x  = (const float*)d_in[0];
    const float* cb = (const float*)d_in[1];
    float* out = (float*)d_out;
    float* ws  = (float*)d_ws;

    float* norms    = ws;
    int*   idx      = (int*)(ws + 1024);
    int*   counts   = (int*)(ws + 66560);
    float* partials = ws + 67584;
    float* cbT      = ws + 71680;

    float* ste     = out;                     // [0, 4194304)
    float* scalars = out + TOTAL_ELEMS;       // pplx, cb_loss, commit
    float* idxf    = out + TOTAL_ELEMS + 3;   // indices as float

    k_prep  <<<4,    256, 0, stream>>>(cb, norms, counts, cbT);
    k_assign<<<512,  512, 0, stream>>>(x, cb, norms, idx, idxf);
    k_quant <<<4096, 256, 0, stream>>>(x, cbT, idx, ste, partials);
    k_hist  <<<256,  256, 0, stream>>>(idx, counts);
    k_final <<<1,   1024, 0, stream>>>(partials, counts, scalars);
}

// Round 3
// 180.073 us; speedup vs baseline: 1.5309x; 1.5309x over previous
//
#include <hip/hip_runtime.h>

typedef __attribute__((ext_vector_type(8))) short short8;
typedef __attribute__((ext_vector_type(4))) float f32x4;

#define N_ROWS   65536
#define DIM      64
#define K_CODES  1024
#define TOTAL_ELEMS 4194304   // N_ROWS * DIM
#define THETA    1e-3f        // cert margin: worst |our_dist - ref_dist| ~1e-4, 10x slack

// ---------------- ws layout (4-byte units) ----------------
// [0      , 1024 )   norms ||e_k||^2 (float, numpy-order)
// [1024   , 66560)   indices (int)
// [66560  , 67584)   counts (int)
// [67584  , 71680)   loss partials (float)
// [71680  , 137216)  cbT[k][d] f32
// [137216 , 169984)  cb_hi[k][d] bf16 (ushort)
// [169984 , 202752)  cb_lo[k][d] bf16 (ushort)
// [202752]           flag counter (int)
// [202753 , 268289)  flag list (int)

__device__ __forceinline__ unsigned short f2bf(float f) {
    union { float f; unsigned int u; } c; c.f = f;
    unsigned int u = c.u;
    return (unsigned short)((u + 0x7fffu + ((u >> 16) & 1u)) >> 16);  // RNE
}
__device__ __forceinline__ float bf2f(unsigned short b) {
    union { unsigned int u; float f; } c; c.u = ((unsigned int)b) << 16;
    return c.f;
}
__device__ __forceinline__ f32x4 MFMA(short8 a, short8 b, f32x4 c) {
    return __builtin_amdgcn_mfma_f32_16x16x32_bf16(a, b, c, 0, 0, 0);
}

// norms (numpy axis-0 order), cbT f32, bf16 hi/lo split; zero counts + flagcnt.
__global__ __launch_bounds__(256) void k_prep(const float* __restrict__ cb,
                                              float* __restrict__ norms,
                                              int* __restrict__ counts,
                                              float* __restrict__ cbT,
                                              unsigned short* __restrict__ cb_hi,
                                              unsigned short* __restrict__ cb_lo,
                                              int* __restrict__ flagcnt) {
    int k = blockIdx.x * 256 + threadIdx.x;   // 4 blocks -> 1024
    float v0 = cb[k];
    float s = __fmul_rn(v0, v0);
    cbT[k * DIM] = v0;
    { unsigned short hb = f2bf(v0); cb_hi[k * DIM] = hb; cb_lo[k * DIM] = f2bf(v0 - bf2f(hb)); }
#pragma unroll 4
    for (int d = 1; d < DIM; ++d) {
        float v = cb[d * K_CODES + k];
        s = __fadd_rn(s, __fmul_rn(v, v));
        cbT[k * DIM + d] = v;
        unsigned short hb = f2bf(v);
        cb_hi[k * DIM + d] = hb;
        cb_lo[k * DIM + d] = f2bf(v - bf2f(hb));
    }
    norms[k] = s;
    counts[k] = 0;
    if (k == 0) flagcnt[0] = 0;
}

// Phase 1: split-bf16 MFMA distance argmin with certificate.
// Block: 256 thr = 4 waves; 64 rows x 1024 codes; wave w owns codes [w*256,(w+1)*256).
__global__ __launch_bounds__(256, 2) void k_assign(const float* __restrict__ x,
                                                   const float* __restrict__ norms,
                                                   const unsigned short* __restrict__ cb_hi,
                                                   const unsigned short* __restrict__ cb_lo,
                                                   int* __restrict__ idx_out,
                                                   float* __restrict__ idxf_out,
                                                   int* __restrict__ flagcnt,
                                                   int* __restrict__ flaglist) {
    __shared__ __align__(16) unsigned short xs_hi[64 * 64];  // XOR-swizzled
    __shared__ __align__(16) unsigned short xs_lo[64 * 64];
    __shared__ float xxs[64];
    __shared__ float mv1[4][64];
    __shared__ float mv2[4][64];
    __shared__ int   mk1[4][64];

    const int tid = threadIdx.x;
    const int r0 = blockIdx.x * 64;

    // Stage X tile -> bf16 hi/lo, swizzle byte5 ^= row&7 (conflict-free b128 frag reads)
#pragma unroll
    for (int i = 0; i < 2; ++i) {
        int c = i * 256 + tid;          // 512 chunk-pairs: 64 rows x 8 x 16B
        int row = c >> 3, ch = c & 7;
        const float4* src = reinterpret_cast<const float4*>(x + (size_t)(r0 + row) * DIM + ch * 8);
        float4 f0 = src[0], f1 = src[1];
        float f[8] = {f0.x, f0.y, f0.z, f0.w, f1.x, f1.y, f1.z, f1.w};
        union { short8 v; unsigned short u[8]; } h, l;
#pragma unroll
        for (int j = 0; j < 8; ++j) {
            unsigned short hb = f2bf(f[j]);
            h.u[j] = hb;
            l.u[j] = f2bf(f[j] - bf2f(hb));
        }
        int eo = row * 64 + ((((ch * 16) ^ ((row & 7) << 4))) >> 1);
        *reinterpret_cast<short8*>(&xs_hi[eo]) = h.v;
        *reinterpret_cast<short8*>(&xs_lo[eo]) = l.v;
    }
    // ||x||^2 per row, numpy pairwise order (must match reference bit-exactly)
    if (tid < 64) {
        const float* xr = x + (size_t)(r0 + tid) * DIM;
        float r[8];
#pragma unroll
        for (int j = 0; j < 8; ++j) { float v = xr[j]; r[j] = __fmul_rn(v, v); }
#pragma unroll
        for (int m = 1; m < 8; ++m)
#pragma unroll
            for (int j = 0; j < 8; ++j) { float v = xr[8 * m + j]; r[j] = __fadd_rn(r[j], __fmul_rn(v, v)); }
        float t01 = __fadd_rn(r[0], r[1]), t23 = __fadd_rn(r[2], r[3]);
        float t45 = __fadd_rn(r[4], r[5]), t67 = __fadd_rn(r[6], r[7]);
        xxs[tid] = __fadd_rn(__fadd_rn(t01, t23), __fadd_rn(t45, t67));
    }
    __syncthreads();

    const int wave = tid >> 6, lane = tid & 63;
    const int lr = lane & 15, lg = lane >> 4;

    // A-frags: lane holds A[row=lr(+16rt)][k=(lg*8)+kh*32 ..+8], 8 consecutive bf16
    short8 a_hi[4][2], a_lo[4][2];
#pragma unroll
    for (int rt = 0; rt < 4; ++rt)
#pragma unroll
        for (int kh = 0; kh < 2; ++kh) {
            int row = rt * 16 + lr;
            int bo = (kh * 64 + lg * 16) ^ ((row & 7) << 4);
            int eo = row * 64 + (bo >> 1);
            a_hi[rt][kh] = *reinterpret_cast<const short8*>(&xs_hi[eo]);
            a_lo[rt][kh] = *reinterpret_cast<const short8*>(&xs_lo[eo]);
        }
    float xxv[16];
#pragma unroll
    for (int rt = 0; rt < 4; ++rt)
#pragma unroll
        for (int r = 0; r < 4; ++r) xxv[rt * 4 + r] = xxs[rt * 16 + lg * 4 + r];

    float v1[16], v2[16]; int k1[16];
#pragma unroll
    for (int i = 0; i < 16; ++i) { v1[i] = 3.4e38f; v2[i] = 3.4e38f; k1[i] = 0; }

    for (int ct = 0; ct < 16; ++ct) {
        int code = wave * 256 + ct * 16 + lr;   // ascending per lane: lowest-k on tie
        float ee = norms[code];
        // B-frags from global (L2-resident): lane holds B[k=(lg*8)+kh*32..+8][col=lr]
        const short8* bh = reinterpret_cast<const short8*>(cb_hi + (size_t)code * DIM);
        const short8* bl = reinterpret_cast<const short8*>(cb_lo + (size_t)code * DIM);
        short8 bh0 = bh[lg], bh1 = bh[4 + lg];
        short8 bl0 = bl[lg], bl1 = bl[4 + lg];

#pragma unroll
        for (int rt = 0; rt < 4; ++rt) {
            f32x4 acc = {0.f, 0.f, 0.f, 0.f};
            acc = MFMA(a_hi[rt][0], bh0, acc); acc = MFMA(a_hi[rt][1], bh1, acc);
            acc = MFMA(a_hi[rt][0], bl0, acc); acc = MFMA(a_hi[rt][1], bl1, acc);
            acc = MFMA(a_lo[rt][0], bh0, acc); acc = MFMA(a_lo[rt][1], bh1, acc);
            acc = MFMA(a_lo[rt][0], bl0, acc); acc = MFMA(a_lo[rt][1], bl1, acc);
#pragma unroll
            for (int r = 0; r < 4; ++r) {
                int i = rt * 4 + r;
                float d = __fsub_rn(__fadd_rn(xxv[i], ee), 2.0f * acc[r]);  // 2*m exact
                bool lt = d < v1[i];
                v2[i] = lt ? v1[i] : fminf(v2[i], d);
                k1[i] = lt ? code : k1[i];
                v1[i] = lt ? d : v1[i];
            }
        }
    }

    // reduce (min1,k1,min2) across 16 col-lanes per row; tie -> lowest k
#pragma unroll
    for (int i = 0; i < 16; ++i) {
        float a1 = v1[i], a2 = v2[i]; int ak = k1[i];
#pragma unroll
        for (int off = 1; off <= 8; off <<= 1) {
            float o1 = __shfl_xor(a1, off);
            float o2 = __shfl_xor(a2, off);
            int   ok = __shfl_xor(ak, off);
            float n2 = fminf(fmaxf(a1, o1), fminf(a2, o2));  // 2nd-min of union
            if (o1 < a1 || (o1 == a1 && ok < ak)) { a1 = o1; ak = ok; }
            a2 = n2;
        }
        if (lr == 0) {
            int row = (i >> 2) * 16 + lg * 4 + (i & 3);
            mv1[wave][row] = a1; mv2[wave][row] = a2; mk1[wave][row] = ak;
        }
    }
    __syncthreads();

    // merge 4 waves (ascending code ranges), certify or flag
    if (tid < 64) {
        float V1 = mv1[0][tid], V2 = mv2[0][tid]; int K1 = mk1[0][tid];
#pragma unroll
        for (int w = 1; w < 4; ++w) {
            float a1 = mv1[w][tid], a2 = mv2[w][tid]; int ak = mk1[w][tid];
            float n2 = fminf(fmaxf(V1, a1), fminf(V2, a2));
            if (a1 < V1) { V1 = a1; K1 = ak; }   // tie keeps lower-code wave
            V2 = n2;
        }
        int rg = r0 + tid;
        if (V2 - V1 <= THETA) {
            int p = atomicAdd(flagcnt, 1);       // set deterministic, order irrelevant
            flaglist[p] = rg;
        } else {
            idx_out[rg]  = K1;
            idxf_out[rg] = (float)K1;
        }
    }
}

// Phase 2: exact (round-2 fp64) re-rank of flagged rows only.
__global__ __launch_bounds__(256) void k_exact(const float* __restrict__ x,
                                               const float* __restrict__ cbT,
                                               const float* __restrict__ norms,
                                               const int* __restrict__ flagcnt,
                                               const int* __restrict__ flaglist,
                                               int* __restrict__ idx_out,
                                               float* __restrict__ idxf_out) {
    __shared__ float xrow[64];
    __shared__ float xxsh;
    __shared__ float rv[4]; __shared__ int rk[4];
    const int tid = threadIdx.x;
    const int cnt = flagcnt[0];
    for (int it = blockIdx.x; it < cnt; it += gridDim.x) {
        __syncthreads();   // protect xrow/rv reuse across iterations
        int row = flaglist[it];
        if (tid < 64) xrow[tid] = x[(size_t)row * DIM + tid];
        __syncthreads();
        if (tid == 0) {
            float r[8];
#pragma unroll
            for (int j = 0; j < 8; ++j) { float v = xrow[j]; r[j] = __fmul_rn(v, v); }
#pragma unroll
            for (int m = 1; m < 8; ++m)
#pragma unroll
                for (int j = 0; j < 8; ++j) { float v = xrow[8 * m + j]; r[j] = __fadd_rn(r[j], __fmul_rn(v, v)); }
            float t01 = __fadd_rn(r[0], r[1]), t23 = __fadd_rn(r[2], r[3]);
            float t45 = __fadd_rn(r[4], r[5]), t67 = __fadd_rn(r[6], r[7]);
            xxsh = __fadd_rn(__fadd_rn(t01, t23), __fadd_rn(t45, t67));
        }
        __syncthreads();
        float xx = xxsh;
        float bv = 3.4e38f; int bk = 0x7fffffff;
        for (int j = 0; j < 4; ++j) {
            int k = j * 256 + tid;
            const float* cr = cbT + (size_t)k * DIM;
            double acc = 0.0;
#pragma unroll
            for (int d = 0; d < DIM; ++d) acc += (double)xrow[d] * (double)cr[d];
            float m = (float)acc;
            float dist = __fsub_rn(__fadd_rn(xx, norms[k]), __fmul_rn(2.0f, m));
            if (dist < bv) { bv = dist; bk = k; }   // ascending k per thread
        }
        int lane = tid & 63, wv = tid >> 6;
#pragma unroll
        for (int off = 1; off <= 32; off <<= 1) {
            float ov = __shfl_xor(bv, off); int ok = __shfl_xor(bk, off);
            if (ov < bv || (ov == bv && ok < bk)) { bv = ov; bk = ok; }
        }
        if (lane == 0) { rv[wv] = bv; rk[wv] = bk; }
        __syncthreads();
        if (tid == 0) {
#pragma unroll
            for (int w = 1; w < 4; ++w)
                if (rv[w] < bv || (rv[w] == bv && rk[w] < bk)) { bv = rv[w]; bk = rk[w]; }
            idx_out[row]  = bk;
            idxf_out[row] = (float)bk;
        }
    }
}

// Gather quantized vectors, STE output, per-block partial of sum((q-x)^2)
__global__ __launch_bounds__(256) void k_quant(const float* __restrict__ x,
                                               const float* __restrict__ cbT,
                                               const int* __restrict__ idx,
                                               float* __restrict__ ste,
                                               float* __restrict__ partials) {
    int t  = blockIdx.x * 256 + threadIdx.x;
    int e  = t << 2;
    int n  = e >> 6;
    int dc = e & 63;
    float4 xv = *reinterpret_cast<const float4*>(x + e);
    int k = idx[n];
    float4 qv = *reinterpret_cast<const float4*>(cbT + (size_t)k * DIM + dc);

    float4 sv;
    sv.x = xv.x + (qv.x - xv.x);
    sv.y = xv.y + (qv.y - xv.y);
    sv.z = xv.z + (qv.z - xv.z);
    sv.w = xv.w + (qv.w - xv.w);
    *reinterpret_cast<float4*>(ste + e) = sv;

    float dx = qv.x - xv.x, dy = qv.y - xv.y, dz = qv.z - xv.z, dw = qv.w - xv.w;
    float s = dx * dx + dy * dy + dz * dz + dw * dw;

#pragma unroll
    for (int off = 32; off >= 1; off >>= 1) s += __shfl_down(s, off);
    __shared__ float red[4];
    int wave = threadIdx.x >> 6, lane = threadIdx.x & 63;
    if (lane == 0) red[wave] = s;
    __syncthreads();
    if (threadIdx.x == 0)
        partials[blockIdx.x] = (red[0] + red[1]) + (red[2] + red[3]);
}

__global__ __launch_bounds__(256) void k_hist(const int* __restrict__ idx,
                                              int* __restrict__ counts) {
    int t = blockIdx.x * 256 + threadIdx.x;
    atomicAdd(&counts[idx[t]], 1);
}

__global__ __launch_bounds__(1024) void k_final(const float* __restrict__ partials,
                                                const int* __restrict__ counts,
                                                float* __restrict__ out_scalars) {
    int tid = threadIdx.x;
    float s = 0.f;
    for (int i = tid; i < 4096; i += 1024) s += partials[i];
#pragma unroll
    for (int off = 32; off >= 1; off >>= 1) s += __shfl_down(s, off);
    __shared__ float wsum[16];
    int wave = tid >> 6, lane = tid & 63;
    if (lane == 0) wsum[wave] = s;

    float c = (float)counts[tid];
    float p = c * (1.0f / 65536.0f);
    float t = -p * logf(p + 1e-10f);
#pragma unroll
    for (int off = 32; off >= 1; off >>= 1) t += __shfl_down(t, off);
    __shared__ float esum[16];
    if (lane == 0) esum[wave] = t;
    __syncthreads();

    if (tid == 0) {
        float total = 0.f, ent = 0.f;
        for (int w = 0; w < 16; ++w) { total += wsum[w]; ent += esum[w]; }
        float mean = total * (1.0f / (float)TOTAL_ELEMS);
        out_scalars[0] = expf(ent);
        out_scalars[1] = mean;
        out_scalars[2] = 0.25f * mean;
    }
}

extern "C" void kernel_launch(void* const* d_in, const int* in_sizes, int n_in,
                              void* d_out, int out_size, void* d_ws, size_t ws_size,
                              hipStream_t stream) {
    const float* x  = (const float*)d_in[0];
    const float* cb = (const float*)d_in[1];
    float* out = (float*)d_out;
    float* ws  = (float*)d_ws;

    float* norms    = ws;
    int*   idx      = (int*)(ws + 1024);
    int*   counts   = (int*)(ws + 66560);
    float* partials = ws + 67584;
    float* cbT      = ws + 71680;
    unsigned short* cb_hi = (unsigned short*)(ws + 137216);
    unsigned short* cb_lo = (unsigned short*)(ws + 169984);
    int*   flagcnt  = (int*)(ws + 202752);
    int*   flaglist = (int*)(ws + 202753);

    float* ste     = out;
    float* scalars = out + TOTAL_ELEMS;
    float* idxf    = out + TOTAL_ELEMS + 3;

    k_prep  <<<4,    256, 0, stream>>>(cb, norms, counts, cbT, cb_hi, cb_lo, flagcnt);
    k_assign<<<1024, 256, 0, stream>>>(x, norms, cb_hi, cb_lo, idx, idxf, flagcnt, flaglist);
    k_exact <<<256,  256, 0, stream>>>(x, cbT, norms, flagcnt, flaglist, idx, idxf);
    k_quant <<<4096, 256, 0, stream>>>(x, cbT, idx, ste, partials);
    k_hist  <<<256,  256, 0, stream>>>(idx, counts);
    k_final <<<1,   1024, 0, stream>>>(partials, counts, scalars);
}